// Round 3
// baseline (307.101 us; speedup 1.0000x reference)
//
#include <hip/hip_runtime.h>
#include <hip/hip_bf16.h>

// Problem shape (fixed by reference setup_inputs): M = B*S = 8192, K = NX = 1024, N = NF = 4096
#define M_DIM 8192
#define K_DIM 1024
#define N_DIM 4096
#define BM 128
#define BN 128
// LDS geometry (shorts): 3 GEMM operand pairs, [kg:4][row/col:128][8] bf16 per panel
#define PAN_S 4096            // 8 KB panel
#define BUF_S (6 * PAN_S)     // 48 KB per K-tile buffer
#define NBUF 3                // 144 KB total, prefetch depth 2 tiles

typedef __attribute__((ext_vector_type(8))) short bf16x8;
typedef __attribute__((ext_vector_type(4))) float f32x4;

__device__ __forceinline__ short f2bf(float f) {
  unsigned u = __builtin_bit_cast(unsigned, f);
  u = (u + 0x7fffu + ((u >> 16) & 1u)) >> 16;
  return (short)u;
}

__device__ __forceinline__ float gelu_f(float x) {
  float u = 0.7978845608028654f * (x + 0.044715f * x * x * x);
  float e = __expf(2.0f * u);
  float t = 1.0f - 2.0f / (e + 1.0f);
  return 0.5f * x * (1.0f + t);
}

__device__ __forceinline__ void gload16(const void* g, void* l) {
  __builtin_amdgcn_global_load_lds((const __attribute__((address_space(1))) void*)g,
                                   (__attribute__((address_space(3))) void*)l, 16, 0, 0);
}

// ---------------- prep: per-row power-of-2 weight scale ----------------
__global__ void rowmax_kernel(const float* __restrict__ w, float* __restrict__ mw) {
  int row = blockIdx.x * 4 + (threadIdx.x >> 6);
  int lane = threadIdx.x & 63;
  const float4* rp = (const float4*)(w + (size_t)row * N_DIM);
  float m = 0.0f;
#pragma unroll
  for (int it = 0; it < 16; ++it) {
    float4 v = rp[it * 64 + lane];
    m = fmaxf(m, fmaxf(fmaxf(fabsf(v.x), fabsf(v.y)), fmaxf(fabsf(v.z), fabsf(v.w))));
  }
#pragma unroll
  for (int off = 32; off > 0; off >>= 1) m = fmaxf(m, __shfl_xor(m, off, 64));
  if (lane == 0) mw[row] = exp2f(rintf(log2f(m)));
}

// ---------------- prep A: quantize input, pack k-chunk-major [K/8][M][8] bf16 ----------------
__global__ void prep_a_kernel(const float* __restrict__ inp, short* __restrict__ aq,
                              short* __restrict__ ad, short* __restrict__ af) {
  int c = blockIdx.x * 256 + threadIdx.x;   // 1,048,576 chunks
  int kg = c >> 13;
  int m = c & 8191;
  const float* src = inp + (size_t)m * K_DIM + kg * 8;
  float4 x0 = *(const float4*)src;
  float4 x1 = *(const float4*)(src + 4);
  float xs[8] = {x0.x, x0.y, x0.z, x0.w, x1.x, x1.y, x1.z, x1.w};
  bf16x8 vq, vd, vf;
#pragma unroll
  for (int j = 0; j < 8; ++j) {
    float x = xs[j];
    float s = (float)((x > 0.0f) - (x < 0.0f));
    float r = rintf(fabsf(x));
    vq[j] = f2bf(s * fminf(r + 1.0f, 7.0f));
    vd[j] = f2bf(s * fminf(r, 6.0f));
    vf[j] = f2bf(x);
  }
  *(bf16x8*)(aq + (size_t)c * 8) = vq;
  *(bf16x8*)(ad + (size_t)c * 8) = vd;
  *(bf16x8*)(af + (size_t)c * 8) = vf;
}

// ---------------- prep W: quantize weight, pack transposed k-chunk-major [K/8][N][8] bf16 ------
__global__ void prep_w_kernel(const float* __restrict__ w, const float* __restrict__ mw,
                              short* __restrict__ wq, short* __restrict__ wd,
                              short* __restrict__ wf) {
  int c = blockIdx.x * 256 + threadIdx.x;   // 524,288 chunks
  int kg = c >> 12;
  int n = c & 4095;
  bf16x8 vq, vd, vf;
#pragma unroll
  for (int j = 0; j < 8; ++j) {
    float wv = w[(size_t)(kg * 8 + j) * N_DIM + n];
    float sc = mw[kg * 8 + j];
    float s = (float)((wv > 0.0f) - (wv < 0.0f));
    float r = rintf(fabsf(wv) / sc * 8.0f);
    vq[j] = f2bf(s * fminf(r + 1.0f, 7.0f));
    vd[j] = f2bf(s * fminf(r, 6.0f) * 0.125f * sc);
    vf[j] = f2bf(wv);
  }
  *(bf16x8*)(wq + (size_t)c * 8) = vq;
  *(bf16x8*)(wd + (size_t)c * 8) = vd;
  *(bf16x8*)(wf + (size_t)c * 8) = vf;
}

// ---------------- fused triple GEMM + select + GELU, pipelined ----------------
// 128x128 tile, BK=32, 512 thr (8 waves 2x4), per-wave 64x32 per GEMM.
// 3-buffer LDS ring (144 KB), prefetch 2 tiles ahead, counted vmcnt(6) at tile
// boundaries (never 0 in steady state), 3 phases/tile (one per GEMM), setprio
// around each 8-MFMA cluster. Packing is k-chunk-major -> conflict-free b128
// reads AND linear global_load_lds dests (no swizzle needed; measured 0 conflicts).
__global__ __launch_bounds__(512, 2) void fused_gemm_kernel(
    const short* __restrict__ aq, const short* __restrict__ ad, const short* __restrict__ af,
    const short* __restrict__ wq, const short* __restrict__ wd, const short* __restrict__ wf,
    const float* __restrict__ bias, float* __restrict__ out) {
  extern __shared__ short lds[];

  const int tid = threadIdx.x;
  const int wid = tid >> 6;
  const int lane = tid & 63;

  // XCD-aware swizzle: 2048 blocks, 8 XCDs -> 256 contiguous tiles per XCD (bijective)
  int bid = blockIdx.x;
  bid = (bid & 7) * 256 + (bid >> 3);
  const int bm0 = (bid >> 5) * BM;   // 64 m-tiles
  const int bn0 = (bid & 31) * BN;   // 32 n-tiles

  const int wr = wid >> 2;           // 0..1 -> 64 rows each
  const int wc = wid & 3;            // 0..3 -> 32 cols each

  const short* APTR[3] = {aq, ad, af};
  const short* BPTR[3] = {wq, wd, wf};

  f32x4 acc[3][4][2];
#pragma unroll
  for (int q = 0; q < 3; ++q)
#pragma unroll
    for (int mf = 0; mf < 4; ++mf)
#pragma unroll
      for (int nf = 0; nf < 2; ++nf) acc[q][mf][nf] = (f32x4){0.f, 0.f, 0.f, 0.f};

  // staging geometry: 512 chunks per panel = [kg:4][rowcol:128]; chunk idx == tid
  const int kgS = wid >> 1;                 // k-group handled by this wave
  const int rbS = ((wid & 1) << 6) + lane;  // row/col handled by this lane

  // fragment offsets (shorts): lane quarter-group g = k-subgroup
  const int g = lane >> 4, rl = lane & 15;
  const int aoff = (g * 128 + wr * 64 + rl) * 8;  // + q*PAN_S + mf*128
  const int boff = (g * 128 + wc * 32 + rl) * 8;  // + (3+q)*PAN_S + nf*128

  // issue one tile's 6 loads (A_q,B_q interleaved, fixed order for vmcnt counting)
  auto stage = [&](int t, int b) {
    const int ca = (t * 4 + kgS) * M_DIM + bm0 + rbS;
    const int cb = (t * 4 + kgS) * N_DIM + bn0 + rbS;
#pragma unroll
    for (int q = 0; q < 3; ++q) {
      gload16(APTR[q] + (size_t)ca * 8, (void*)&lds[b * BUF_S + q * PAN_S + tid * 8]);
      gload16(BPTR[q] + (size_t)cb * 8, (void*)&lds[b * BUF_S + (3 + q) * PAN_S + tid * 8]);
    }
  };

  stage(0, 0);
  stage(1, 1);   // 12 loads in flight

  for (int t = 0; t < 32; ++t) {
    const int b = t % 3;
    const int t2 = t + 2;
    const int b2 = t2 % 3;
    // tile-t data ready: 6 loads of tile t+1 may stay in flight (counted wait)
    if (t <= 30)
      asm volatile("s_waitcnt vmcnt(6)" ::: "memory");
    else
      asm volatile("s_waitcnt vmcnt(0)" ::: "memory");
    __builtin_amdgcn_s_barrier();
    __builtin_amdgcn_sched_barrier(0);  // nothing moves above the barrier

#pragma unroll
    for (int q = 0; q < 3; ++q) {
      bf16x8 aF[4], bF[2];
#pragma unroll
      for (int mf = 0; mf < 4; ++mf)
        aF[mf] = *(const bf16x8*)&lds[b * BUF_S + q * PAN_S + aoff + mf * 128];
#pragma unroll
      for (int nf = 0; nf < 2; ++nf)
        bF[nf] = *(const bf16x8*)&lds[b * BUF_S + (3 + q) * PAN_S + boff + nf * 128];

      if (t2 < 32) {  // prefetch this GEMM's panels of tile t+2 (2 loads/phase)
        const int ca = (t2 * 4 + kgS) * M_DIM + bm0 + rbS;
        const int cb = (t2 * 4 + kgS) * N_DIM + bn0 + rbS;
        gload16(APTR[q] + (size_t)ca * 8, (void*)&lds[b2 * BUF_S + q * PAN_S + tid * 8]);
        gload16(BPTR[q] + (size_t)cb * 8, (void*)&lds[b2 * BUF_S + (3 + q) * PAN_S + tid * 8]);
      }

      __builtin_amdgcn_s_barrier();  // align waves: everyone issued phase-q loads
      __builtin_amdgcn_s_setprio(1);
#pragma unroll
      for (int mf = 0; mf < 4; ++mf)
#pragma unroll
        for (int nf = 0; nf < 2; ++nf)
          acc[q][mf][nf] = __builtin_amdgcn_mfma_f32_16x16x32_bf16(
              aF[mf], bF[nf], acc[q][mf][nf], 0, 0, 0);
      __builtin_amdgcn_s_setprio(0);
    }
  }

  // epilogue: select by exact integer sign, add (quantized) bias, GELU, store
#pragma unroll
  for (int nf = 0; nf < 2; ++nf) {
    int col = bn0 + wc * 32 + nf * 16 + rl;
    float bv = bias[col];
    float sb = (float)((bv > 0.0f) - (bv < 0.0f));
    float db = sb * fminf(rintf(fabsf(bv)), 6.0f);
#pragma unroll
    for (int mf = 0; mf < 4; ++mf) {
#pragma unroll
      for (int i = 0; i < 4; ++i) {
        int row = bm0 + wr * 64 + mf * 16 + g * 4 + i;
        float s1 = acc[0][mf][nf][i];  // exact integer
        float v = (s1 < 0.0f) ? (acc[1][mf][nf][i] + db) : (acc[2][mf][nf][i] + bv);
        out[(size_t)row * N_DIM + col] = gelu_f(v);
      }
    }
  }
}

extern "C" void kernel_launch(void* const* d_in, const int* in_sizes, int n_in,
                              void* d_out, int out_size, void* d_ws, size_t ws_size,
                              hipStream_t stream) {
  const float* inp = (const float*)d_in[0];
  const float* w = (const float*)d_in[1];
  const float* bias = (const float*)d_in[2];
  float* out = (float*)d_out;

  short* aq = (short*)d_ws;
  short* ad = aq + (size_t)M_DIM * K_DIM;
  short* af = ad + (size_t)M_DIM * K_DIM;
  short* wq = af + (size_t)M_DIM * K_DIM;
  short* wd = wq + (size_t)K_DIM * N_DIM;
  short* wf = wd + (size_t)K_DIM * N_DIM;
  float* mw = (float*)(wf + (size_t)K_DIM * N_DIM);

  static int lds_bytes = NBUF * BUF_S * (int)sizeof(short);  // 147456
  hipFuncSetAttribute((const void*)fused_gemm_kernel,
                      hipFuncAttributeMaxDynamicSharedMemorySize, lds_bytes);

  rowmax_kernel<<<K_DIM / 4, 256, 0, stream>>>(w, mw);
  prep_a_kernel<<<(M_DIM / 8) * (K_DIM / 256), 256, 0, stream>>>(inp, aq, ad, af);
  prep_w_kernel<<<(N_DIM / 8) * (K_DIM / 256), 256, 0, stream>>>(w, mw, wq, wd, wf);
  fused_gemm_kernel<<<(M_DIM / BM) * (N_DIM / BN), 512, lds_bytes, stream>>>(
      aq, ad, af, wq, wd, wf, bias, out);
}

// Round 4
// 203.352 us; speedup vs baseline: 1.5102x; 1.5102x over previous
//
#include <hip/hip_runtime.h>
#include <hip/hip_bf16.h>

// Problem shape: M = B*S = 8192, K = NX = 1024, N = NF = 4096
#define M_DIM 8192
#define K_DIM 1024
#define N_DIM 4096
// Block tile 128(M) x 256(N), BK=32, 8 waves (2x4), per-wave 64x64 via 32x32 frags.
// LDS buffer (48KB): [0,4K) A_i8 [kg16:2][row:128]x16B | [4K,8K) A_fp8 [kg8:4][row:128]x8B
// [8K,16K) A_bf16 [kg8:4][row:128]x16B | [16K,24K) B_i8 [kg16:2][col:256]x16B
// [24K,32K) B_fp8 [kg8:4][col:256]x8B | [32K,48K) B_bf16 [kg8:4][col:256]x16B
#define BUF_BYTES 49152

typedef __attribute__((ext_vector_type(8))) short bf16x8;
typedef __attribute__((ext_vector_type(4))) int i32x4;
typedef __attribute__((ext_vector_type(16))) int i32x16;
typedef __attribute__((ext_vector_type(16))) float f32x16;

__device__ __forceinline__ short f2bf(float f) {
  unsigned u = __builtin_bit_cast(unsigned, f);
  u = (u + 0x7fffu + ((u >> 16) & 1u)) >> 16;
  return (short)u;
}

// f32 -> OCP e4m3fn, exact for our value set (small ints x 2^e)
__device__ __forceinline__ unsigned f2fp8(float v) {
  unsigned b = __builtin_bit_cast(unsigned, v);
  unsigned sg = (b >> 24) & 0x80u;
  unsigned ab = b & 0x7fffffffu;
  if (ab == 0) return sg;
  int e = (int)(ab >> 23) - 127;
  unsigned m3 = (ab >> 20) & 7u;
  if (e >= -6) return sg | (unsigned)((e + 7) << 3) | m3;
  return sg | ((8u + m3) >> (-6 - e));  // subnormal (exact for our values)
}

__device__ __forceinline__ float gelu_f(float x) {
  float u = 0.7978845608028654f * (x + 0.044715f * x * x * x);
  float e = __expf(2.0f * u);
  float t = 1.0f - 2.0f / (e + 1.0f);
  return 0.5f * x * (1.0f + t);
}

__device__ __forceinline__ void gload16(const void* g, void* l) {
  __builtin_amdgcn_global_load_lds((const __attribute__((address_space(1))) void*)g,
                                   (__attribute__((address_space(3))) void*)l, 16, 0, 0);
}

// ---------------- per-k power-of-2 weight scale ----------------
__global__ void rowmax_kernel(const float* __restrict__ w, float* __restrict__ mw) {
  int row = blockIdx.x * 4 + (threadIdx.x >> 6);
  int lane = threadIdx.x & 63;
  const float4* rp = (const float4*)(w + (size_t)row * N_DIM);
  float m = 0.0f;
#pragma unroll
  for (int it = 0; it < 16; ++it) {
    float4 v = rp[it * 64 + lane];
    m = fmaxf(m, fmaxf(fmaxf(fabsf(v.x), fabsf(v.y)), fmaxf(fabsf(v.z), fabsf(v.w))));
  }
#pragma unroll
  for (int off = 32; off > 0; off >>= 1) m = fmaxf(m, __shfl_xor(m, off, 64));
  if (lane == 0) mw[row] = exp2f(rintf(log2f(m)));
}

// ---------------- prep A: one thread per (kg16, m); 16 k-values ----------------
__global__ void prep_a_kernel(const float* __restrict__ inp, signed char* __restrict__ aqi,
                              unsigned char* __restrict__ adf, short* __restrict__ af) {
  int c = blockIdx.x * 256 + threadIdx.x;   // [kg16:64][m:8192]
  int kg = c >> 13, m = c & 8191;
  const float4* src = (const float4*)(inp + (size_t)m * K_DIM + kg * 16);
  float xs[16];
#pragma unroll
  for (int v = 0; v < 4; ++v) {
    float4 t = src[v];
    xs[v * 4 + 0] = t.x; xs[v * 4 + 1] = t.y; xs[v * 4 + 2] = t.z; xs[v * 4 + 3] = t.w;
  }
  int qi[4] = {0, 0, 0, 0};
  unsigned long long f8lo = 0ull, f8hi = 0ull;
  bf16x8 b0, b1;
#pragma unroll
  for (int j = 0; j < 16; ++j) {
    float x = xs[j];
    float s = (x > 0.f) ? 1.f : ((x < 0.f) ? -1.f : 0.f);
    float r = rintf(fabsf(x));
    int iq = (int)(s * fminf(r + 1.f, 7.f));     // in_q, exact small int
    qi[j >> 2] |= (iq & 255) << ((j & 3) * 8);
    unsigned f8 = f2fp8(s * fminf(r, 6.f));      // deq(in_q)
    if (j < 8) f8lo |= (unsigned long long)f8 << (j * 8);
    else       f8hi |= (unsigned long long)f8 << ((j - 8) * 8);
    short bb = f2bf(x);
    if (j < 8) b0[j] = bb; else b1[j - 8] = bb;
  }
  *(i32x4*)(aqi + ((size_t)kg * M_DIM + m) * 16) = (i32x4){qi[0], qi[1], qi[2], qi[3]};
  *(unsigned long long*)(adf + ((size_t)(2 * kg) * M_DIM + m) * 8) = f8lo;
  *(unsigned long long*)(adf + ((size_t)(2 * kg + 1) * M_DIM + m) * 8) = f8hi;
  *(bf16x8*)(af + ((size_t)(2 * kg) * M_DIM + m) * 8) = b0;
  *(bf16x8*)(af + ((size_t)(2 * kg + 1) * M_DIM + m) * 8) = b1;
}

// ---------------- prep W: one thread per (kg16, n) ----------------
__global__ void prep_w_kernel(const float* __restrict__ w, const float* __restrict__ mw,
                              signed char* __restrict__ wqi, unsigned char* __restrict__ wdf,
                              short* __restrict__ wf) {
  int c = blockIdx.x * 256 + threadIdx.x;   // [kg16:64][n:4096]
  int kg = c >> 12, n = c & 4095;
  int qi[4] = {0, 0, 0, 0};
  unsigned long long f8lo = 0ull, f8hi = 0ull;
  bf16x8 b0, b1;
#pragma unroll
  for (int j = 0; j < 16; ++j) {
    float wv = w[(size_t)(kg * 16 + j) * N_DIM + n];
    float sc = mw[kg * 16 + j];                  // wave-uniform
    float s = (wv > 0.f) ? 1.f : ((wv < 0.f) ? -1.f : 0.f);
    float r = rintf(fabsf(wv) * (8.0f / sc));    // exact: 8/sc is a power of 2
    int iq = (int)(s * fminf(r + 1.f, 7.f));     // w_q
    qi[j >> 2] |= (iq & 255) << ((j & 3) * 8);
    unsigned f8 = f2fp8(s * fminf(r, 6.f) * 0.125f * sc);  // deq(w_q), exact in e4m3
    if (j < 8) f8lo |= (unsigned long long)f8 << (j * 8);
    else       f8hi |= (unsigned long long)f8 << ((j - 8) * 8);
    short bb = f2bf(wv);
    if (j < 8) b0[j] = bb; else b1[j - 8] = bb;
  }
  *(i32x4*)(wqi + ((size_t)kg * N_DIM + n) * 16) = (i32x4){qi[0], qi[1], qi[2], qi[3]};
  *(unsigned long long*)(wdf + ((size_t)(2 * kg) * N_DIM + n) * 8) = f8lo;
  *(unsigned long long*)(wdf + ((size_t)(2 * kg + 1) * N_DIM + n) * 8) = f8hi;
  *(bf16x8*)(wf + ((size_t)(2 * kg) * N_DIM + n) * 8) = b0;
  *(bf16x8*)(wf + ((size_t)(2 * kg + 1) * N_DIM + n) * 8) = b1;
}

// ---------------- fused triple GEMM (i8 + fp8 + bf16) + select + GELU ----------------
__global__ __launch_bounds__(512, 2) void fused_gemm_kernel(
    const signed char* __restrict__ aqi, const unsigned char* __restrict__ adf,
    const short* __restrict__ af, const signed char* __restrict__ wqi,
    const unsigned char* __restrict__ wdf, const short* __restrict__ wf,
    const float* __restrict__ bias, float* __restrict__ out) {
  extern __shared__ char lds[];

  const int tid = threadIdx.x;
  const int wid = tid >> 6;
  const int lane = tid & 63;

  // XCD swizzle: 1024 blocks, 8 XCDs -> 128 contiguous tiles per XCD (bijective)
  int bid = blockIdx.x;
  bid = (bid & 7) * 128 + (bid >> 3);
  const int bm0 = (bid >> 4) * 128;   // 64 m-tiles
  const int bn0 = (bid & 15) * 256;   // 16 n-tiles

  const int wr = wid >> 2;   // 0..1 -> 64 rows
  const int wc = wid & 3;    // 0..3 -> 64 cols

  // ---- staging slots: 48 units of 1KB per K-step, 6 per wave (uniform for vmcnt) ----
  const char* gb[6]; int gs[6]; int lo[6];
#pragma unroll
  for (int i = 0; i < 6; ++i) {
    int u = wid * 6 + i;
    lo[i] = u * 1024 + lane * 16;
    if (u < 4) {                                        // A_i8
      int o = u * 64 + lane; int kg = o >> 7, row = o & 127;
      gb[i] = (const char*)aqi + (size_t)(kg * M_DIM + bm0 + row) * 16;
      gs[i] = 32 * M_DIM;
    } else if (u < 8) {                                 // A_fp8 (2 rows per 16B)
      int kg = u - 4;
      gb[i] = (const char*)adf + (size_t)(kg * M_DIM + bm0) * 8 + lane * 16;
      gs[i] = 32 * M_DIM;
    } else if (u < 16) {                                // A_bf16
      int o = (u - 8) * 64 + lane; int kg = o >> 7, row = o & 127;
      gb[i] = (const char*)af + (size_t)(kg * M_DIM + bm0 + row) * 16;
      gs[i] = 64 * M_DIM;
    } else if (u < 24) {                                // B_i8
      int o = (u - 16) * 64 + lane; int kg = o >> 8, col = o & 255;
      gb[i] = (const char*)wqi + (size_t)(kg * N_DIM + bn0 + col) * 16;
      gs[i] = 32 * N_DIM;
    } else if (u < 32) {                                // B_fp8 (2 cols per 16B)
      int uu = u - 24; int kg = uu >> 1; int col = (uu & 1) * 128 + lane * 2;
      gb[i] = (const char*)wdf + (size_t)(kg * N_DIM + bn0 + col) * 8;
      gs[i] = 32 * N_DIM;
    } else {                                            // B_bf16
      int o = (u - 32) * 64 + lane; int kg = o >> 8, col = o & 255;
      gb[i] = (const char*)wf + (size_t)(kg * N_DIM + bn0 + col) * 16;
      gs[i] = 64 * N_DIM;
    }
  }

  // fragment geometry (32x32 shapes): row/col = lane&31, k-half = lane>>5
  const int h = lane >> 5;
  const int l31 = lane & 31;
  const int ra = wr * 64 + l31;
  const int rb = wc * 64 + l31;

  i32x16 acc0[2][2];
  f32x16 acc1[2][2], acc2[2][2];
  const i32x16 zi = {0, 0, 0, 0, 0, 0, 0, 0, 0, 0, 0, 0, 0, 0, 0, 0};
  const f32x16 zf = {0, 0, 0, 0, 0, 0, 0, 0, 0, 0, 0, 0, 0, 0, 0, 0};
#pragma unroll
  for (int mf = 0; mf < 2; ++mf)
#pragma unroll
    for (int nf = 0; nf < 2; ++nf) { acc0[mf][nf] = zi; acc1[mf][nf] = zf; acc2[mf][nf] = zf; }

  // prologue: tile 0 -> buf0
#pragma unroll
  for (int i = 0; i < 6; ++i) gload16(gb[i], lds + lo[i]);

  for (int t = 0; t < 32; ++t) {
    const int cb = (t & 1) * BUF_BYTES;
    if (t < 31) {
      const int nb = ((t + 1) & 1) * BUF_BYTES;
#pragma unroll
      for (int i = 0; i < 6; ++i)
        gload16(gb[i] + (size_t)(t + 1) * gs[i], lds + nb + lo[i]);
      asm volatile("s_waitcnt vmcnt(6)" ::: "memory");  // tile t done, t+1 in flight
    } else {
      asm volatile("s_waitcnt vmcnt(0)" ::: "memory");
    }
    __builtin_amdgcn_s_barrier();
    __builtin_amdgcn_sched_barrier(0);

    const char* B = lds + cb;
    // ---- q0: i8 sign GEMM (exact) ----
    {
      i32x4 a0[2], b0[2];
#pragma unroll
      for (int mf = 0; mf < 2; ++mf)
        a0[mf] = *(const i32x4*)(B + (h * 128 + ra + mf * 32) * 16);
#pragma unroll
      for (int nf = 0; nf < 2; ++nf)
        b0[nf] = *(const i32x4*)(B + 16384 + (h * 256 + rb + nf * 32) * 16);
#pragma unroll
      for (int mf = 0; mf < 2; ++mf)
#pragma unroll
        for (int nf = 0; nf < 2; ++nf)
          acc0[mf][nf] =
              __builtin_amdgcn_mfma_i32_32x32x32_i8(a0[mf], b0[nf], acc0[mf][nf], 0, 0, 0);
    }
    // ---- q1: fp8 dequant GEMM (exact) ----
#pragma unroll
    for (int kg = 0; kg < 2; ++kg) {
      long a1[2], b1[2];
#pragma unroll
      for (int mf = 0; mf < 2; ++mf)
        a1[mf] = *(const long*)(B + 4096 + ((kg * 2 + h) * 128 + ra + mf * 32) * 8);
#pragma unroll
      for (int nf = 0; nf < 2; ++nf)
        b1[nf] = *(const long*)(B + 24576 + ((kg * 2 + h) * 256 + rb + nf * 32) * 8);
#pragma unroll
      for (int mf = 0; mf < 2; ++mf)
#pragma unroll
        for (int nf = 0; nf < 2; ++nf)
          acc1[mf][nf] = __builtin_amdgcn_mfma_f32_32x32x16_fp8_fp8(a1[mf], b1[nf],
                                                                    acc1[mf][nf], 0, 0, 0);
    }
    // ---- q2: bf16 full GEMM ----
#pragma unroll
    for (int kg = 0; kg < 2; ++kg) {
      bf16x8 a2[2], b2[2];
#pragma unroll
      for (int mf = 0; mf < 2; ++mf)
        a2[mf] = *(const bf16x8*)(B + 8192 + ((kg * 2 + h) * 128 + ra + mf * 32) * 16);
#pragma unroll
      for (int nf = 0; nf < 2; ++nf)
        b2[nf] = *(const bf16x8*)(B + 32768 + ((kg * 2 + h) * 256 + rb + nf * 32) * 16);
#pragma unroll
      for (int mf = 0; mf < 2; ++mf)
#pragma unroll
        for (int nf = 0; nf < 2; ++nf)
          acc2[mf][nf] = __builtin_amdgcn_mfma_f32_32x32x16_bf16(a2[mf], b2[nf],
                                                                 acc2[mf][nf], 0, 0, 0);
    }
    asm volatile("s_waitcnt lgkmcnt(0)" ::: "memory");  // all LDS reads of buf done
    __builtin_amdgcn_sched_barrier(0);
    __builtin_amdgcn_s_barrier();                       // safe to overwrite buf next iter
  }

  // ---- epilogue: select by exact integer sign, bias, GELU ----
  // 32x32 C layout: col = lane&31, row = (reg&3) + 8*(reg>>2) + 4*(lane>>5)
#pragma unroll
  for (int nf = 0; nf < 2; ++nf) {
    const int col = bn0 + rb + nf * 32;
    const float bv = bias[col];
    const float sb = (bv > 0.f) ? 1.f : ((bv < 0.f) ? -1.f : 0.f);
    const float db = sb * fminf(rintf(fabsf(bv)), 6.f);
#pragma unroll
    for (int mf = 0; mf < 2; ++mf) {
#pragma unroll
      for (int r = 0; r < 16; ++r) {
        const int row = bm0 + wr * 64 + mf * 32 + (r & 3) + 8 * (r >> 2) + 4 * h;
        float x = (acc0[mf][nf][r] < 0) ? (acc1[mf][nf][r] + db) : (acc2[mf][nf][r] + bv);
        out[(size_t)row * N_DIM + col] = gelu_f(x);
      }
    }
  }
}

extern "C" void kernel_launch(void* const* d_in, const int* in_sizes, int n_in,
                              void* d_out, int out_size, void* d_ws, size_t ws_size,
                              hipStream_t stream) {
  const float* inp = (const float*)d_in[0];
  const float* w = (const float*)d_in[1];
  const float* bias = (const float*)d_in[2];
  float* out = (float*)d_out;

  // workspace: af 16MB | wf 8MB | aqi 8MB | adf 8MB | wqi 4MB | wdf 4MB | mw 4KB
  char* p = (char*)d_ws;
  short* af = (short*)p;             p += (size_t)M_DIM * K_DIM * 2;
  short* wf = (short*)p;             p += (size_t)K_DIM * N_DIM * 2;
  signed char* aqi = (signed char*)p; p += (size_t)M_DIM * K_DIM;
  unsigned char* adf = (unsigned char*)p; p += (size_t)M_DIM * K_DIM;
  signed char* wqi = (signed char*)p; p += (size_t)K_DIM * N_DIM;
  unsigned char* wdf = (unsigned char*)p; p += (size_t)K_DIM * N_DIM;
  float* mw = (float*)p;

  const int lds_bytes = 2 * BUF_BYTES;  // 98304
  hipFuncSetAttribute((const void*)fused_gemm_kernel,
                      hipFuncAttributeMaxDynamicSharedMemorySize, lds_bytes);

  rowmax_kernel<<<K_DIM / 4, 256, 0, stream>>>(w, mw);
  prep_a_kernel<<<(M_DIM * K_DIM / 16) / 256, 256, 0, stream>>>(inp, aqi, adf, af);
  prep_w_kernel<<<(K_DIM * N_DIM / 16) / 256, 256, 0, stream>>>(w, mw, wqi, wdf, wf);
  fused_gemm_kernel<<<(M_DIM / 128) * (N_DIM / 256), 512, lds_bytes, stream>>>(
      aqi, adf, af, wqi, wdf, wf, bias, out);
}